// Round 1
// baseline (708.945 us; speedup 1.0000x reference)
//
#include <hip/hip_runtime.h>
#include <stdint.h>

// Problem constants
#define BB 4
#define LL 2048
#define QQ 16293
#define RR 24
#define DD 32
#define SS 128
#define NLAYER 8
#define OUTW 1792
#define TT0 2047              // length of x after embedding (L-1)
#define MROWS (BB*OUTW)       // 7168
#define NPAD 16384            // padded Q for GEMM tiles

typedef float v4f __attribute__((ext_vector_type(4)));
typedef short v8s __attribute__((ext_vector_type(8)));

static __device__ __forceinline__ unsigned short f2bf(float x) {
  // round-to-nearest-even fp32 -> bf16 (inputs are finite, no NaN handling needed)
  unsigned int u = __float_as_uint(x);
  unsigned int r = (u + 0x7fffu + ((u >> 16) & 1u)) >> 16;
  return (unsigned short)r;
}

// ---------------------------------------------------------------------------
// 1) Embedding: x[b][t][r] = pre_W[0][idx[b][t]][r] + pre_W[1][idx[b][t+1]][r]
// ---------------------------------------------------------------------------
__global__ __launch_bounds__(256) void embed_kernel(const int* __restrict__ idx,
                                                    const float* __restrict__ preW,
                                                    float* __restrict__ x) {
  int tid = blockIdx.x * 256 + threadIdx.x;
  if (tid >= BB * (LL - 1)) return;
  int b = tid / (LL - 1);
  int t = tid - b * (LL - 1);
  int i0 = idx[b * LL + t];
  int i1 = idx[b * LL + t + 1];
  const float4* p0 = (const float4*)(preW + (size_t)i0 * RR);
  const float4* p1 = (const float4*)(preW + (size_t)QQ * RR + (size_t)i1 * RR);
  float4* xo = (float4*)(x + ((size_t)b * TT0 + t) * RR);
#pragma unroll
  for (int k = 0; k < 6; ++k) {
    float4 a = p0[k];
    float4 c = p1[k];
    a.x += c.x; a.y += c.y; a.z += c.z; a.w += c.w;
    xo[k] = a;
  }
}

// ---------------------------------------------------------------------------
// 2) One WaveNet layer (fp32, exact):
//    z = conv2(x, F/G); out = tanh(zf)*sigmoid(zg)
//    skip_sum[b][t-(254-layer)][:] += out @ skip_W
//    x_out[t] = x_in[t+1] + out @ res_W
// Block: 256 thr = 4 waves; lane = t_local (64 t per block), wave w owns
// d-slice [8w,8w+8), skip-slice [32w,32w+32), res-slice [6w,6w+6).
// Weight indices are wave-uniform -> s_load path, no LDS weight traffic.
// ---------------------------------------------------------------------------
__global__ __launch_bounds__(256) void layer_kernel(
    const float* __restrict__ x_in, float* __restrict__ x_out,
    float* __restrict__ skip_sum,
    const float* __restrict__ filtW, const float* __restrict__ gateW,
    const float* __restrict__ resW, const float* __restrict__ skipW,
    int layer, int Tout) {
  int b = blockIdx.y;
  int lane = threadIdx.x & 63;
  int w = __builtin_amdgcn_readfirstlane((int)(threadIdx.x >> 6));
  int t = blockIdx.x * 64 + lane;
  bool valid = t < Tout;

  const float* Fw = filtW + (size_t)layer * 2 * RR * DD;  // [2][24][32]
  const float* Gw = gateW + (size_t)layer * 2 * RR * DD;
  const float* Rw = resW + (size_t)layer * DD * RR;        // [32][24]
  const float* Sw = skipW + (size_t)layer * DD * SS;       // [32][128]

  __shared__ float out_s[64][33];

  float xa[RR], xb[RR];
  if (valid) {
    const float4* xi = (const float4*)(x_in + ((size_t)b * TT0 + t) * RR);
#pragma unroll
    for (int k2 = 0; k2 < 6; ++k2) {
      float4 v = xi[k2];
      xa[4 * k2 + 0] = v.x; xa[4 * k2 + 1] = v.y;
      xa[4 * k2 + 2] = v.z; xa[4 * k2 + 3] = v.w;
    }
#pragma unroll
    for (int k2 = 0; k2 < 6; ++k2) {
      float4 v = xi[6 + k2];
      xb[4 * k2 + 0] = v.x; xb[4 * k2 + 1] = v.y;
      xb[4 * k2 + 2] = v.z; xb[4 * k2 + 3] = v.w;
    }
  } else {
#pragma unroll
    for (int r = 0; r < RR; ++r) { xa[r] = 0.f; xb[r] = 0.f; }
  }

  float zf[8], zg[8];
#pragma unroll
  for (int dd = 0; dd < 8; ++dd) { zf[dd] = 0.f; zg[dd] = 0.f; }
#pragma unroll
  for (int r = 0; r < RR; ++r) {
#pragma unroll
    for (int dd = 0; dd < 8; ++dd) {
      int d = w * 8 + dd;
      zf[dd] = fmaf(xa[r], Fw[r * DD + d], zf[dd]);
      zf[dd] = fmaf(xb[r], Fw[RR * DD + r * DD + d], zf[dd]);
      zg[dd] = fmaf(xa[r], Gw[r * DD + d], zg[dd]);
      zg[dd] = fmaf(xb[r], Gw[RR * DD + r * DD + d], zg[dd]);
    }
  }
#pragma unroll
  for (int dd = 0; dd < 8; ++dd) {
    float o = tanhf(zf[dd]) * (1.0f / (1.0f + expf(-zg[dd])));
    out_s[lane][w * 8 + dd] = o;
  }
  __syncthreads();
  float o[DD];
#pragma unroll
  for (int d = 0; d < DD; ++d) o[d] = out_s[lane][d];

  if (!valid) return;  // no barriers below

  // skip accumulation (row exclusive per thread -> plain RMW)
  int j = t - (254 - layer);
  if (j >= 0) {
    float4* sp = (float4*)(skip_sum + ((size_t)b * OUTW + j) * SS + w * 32);
#pragma unroll
    for (int s4 = 0; s4 < 8; ++s4) {
      float4 v = sp[s4];
      float a0 = 0.f, a1 = 0.f, a2 = 0.f, a3 = 0.f;
#pragma unroll
      for (int d = 0; d < DD; ++d) {
        const float* swp = Sw + d * SS + w * 32 + s4 * 4;
        a0 = fmaf(o[d], swp[0], a0);
        a1 = fmaf(o[d], swp[1], a1);
        a2 = fmaf(o[d], swp[2], a2);
        a3 = fmaf(o[d], swp[3], a3);
      }
      v.x += a0; v.y += a1; v.z += a2; v.w += a3;
      sp[s4] = v;
    }
  }

  // residual transform
  float* xo = x_out + ((size_t)b * TT0 + t) * RR;
#pragma unroll
  for (int rr2 = 0; rr2 < 6; ++rr2) {
    int r = w * 6 + rr2;
    // reload x_in[t+1][r] from global (L1-hot) to avoid dynamic reg indexing
    float acc = x_in[((size_t)b * TT0 + t + 1) * RR + r];
#pragma unroll
    for (int d = 0; d < DD; ++d) acc = fmaf(o[d], Rw[d * RR + r], acc);
    xo[r] = acc;
  }
}

// ---------------------------------------------------------------------------
// 3) h1 = relu(relu(skip_sum) @ post_W1), stored bf16  [7168][128]
// Block: 64 rows x 128 cols; thread = (tr=tid>>5 -> 8 rows, tc=tid&31 -> 4 cols)
// ---------------------------------------------------------------------------
__global__ __launch_bounds__(256) void h1_kernel(const float* __restrict__ skip_sum,
                                                 const float* __restrict__ W1,
                                                 unsigned short* __restrict__ h1) {
  int m0 = blockIdx.x * 64;
  int tc = threadIdx.x & 31;
  int tr = threadIdx.x >> 5;
  __shared__ float h_s[64][128];
#pragma unroll
  for (int it = 0; it < 32; ++it) {
    int lin = it * 256 + (int)threadIdx.x;
    int rrow = lin >> 7, d = lin & 127;
    float v = skip_sum[(size_t)(m0 + rrow) * SS + d];
    h_s[rrow][d] = v > 0.f ? v : 0.f;
  }
  __syncthreads();

  float acc[8][4];
#pragma unroll
  for (int rr = 0; rr < 8; ++rr)
#pragma unroll
    for (int c = 0; c < 4; ++c) acc[rr][c] = 0.f;

#pragma unroll 4
  for (int d = 0; d < 128; ++d) {
    float4 wv = *(const float4*)(W1 + (size_t)d * SS + tc * 4);
#pragma unroll
    for (int rr = 0; rr < 8; ++rr) {
      float hv = h_s[tr * 8 + rr][d];
      acc[rr][0] = fmaf(hv, wv.x, acc[rr][0]);
      acc[rr][1] = fmaf(hv, wv.y, acc[rr][1]);
      acc[rr][2] = fmaf(hv, wv.z, acc[rr][2]);
      acc[rr][3] = fmaf(hv, wv.w, acc[rr][3]);
    }
  }
#pragma unroll
  for (int rr = 0; rr < 8; ++rr) {
    int row = m0 + tr * 8 + rr;
    ushort4 u;
    u.x = f2bf(fmaxf(acc[rr][0], 0.f));
    u.y = f2bf(fmaxf(acc[rr][1], 0.f));
    u.z = f2bf(fmaxf(acc[rr][2], 0.f));
    u.w = f2bf(fmaxf(acc[rr][3], 0.f));
    *(ushort4*)(h1 + (size_t)row * SS + tc * 4) = u;
  }
}

// ---------------------------------------------------------------------------
// 4) W2T: transpose post_W2 [128][16293] -> bf16 [16384][128], zero-padded
// ---------------------------------------------------------------------------
__global__ __launch_bounds__(256) void w2t_kernel(const float* __restrict__ W2,
                                                  unsigned short* __restrict__ W2T) {
  int n0 = blockIdx.x * 64;
  __shared__ float t_s[64][129];
#pragma unroll
  for (int it = 0; it < 32; ++it) {
    int lin = it * 256 + (int)threadIdx.x;
    int k = lin >> 6, nn = lin & 63;
    int n = n0 + nn;
    t_s[nn][k] = (n < QQ) ? W2[(size_t)k * QQ + n] : 0.f;
  }
  __syncthreads();
#pragma unroll
  for (int it = 0; it < 4; ++it) {
    int lin = it * 256 + (int)threadIdx.x;
    int nn = lin >> 4, slot = lin & 15;
    v8s val;
#pragma unroll
    for (int jj = 0; jj < 8; ++jj) val[jj] = (short)f2bf(t_s[nn][slot * 8 + jj]);
    *(v8s*)(W2T + ((size_t)(n0 + nn)) * 128 + slot * 8) = val;
  }
}

// ---------------------------------------------------------------------------
// 5) logits = h1 @ W2  (bf16 MFMA, fp32 accum).  M=7168, N=16384(pad), K=128.
// Block 256 thr (4 waves, 2x2), tile 128x128, K fully resident (no K loop).
// LDS: A_s,B_s 32KB each, [row][k] bf16 with XOR swizzle on 16B granules.
// k-index mapping k = ks*32 + g*8 + j used identically for A and B fragments
// -> result invariant to HW's internal k permutation.
// C/D layout (verified): n = lane&15, m = (lane>>4)*4 + reg.
// ---------------------------------------------------------------------------
__global__ __launch_bounds__(256) void gemm_kernel(const unsigned short* __restrict__ A,
                                                   const unsigned short* __restrict__ Bm,
                                                   float* __restrict__ Cc) {
  __shared__ unsigned short A_s[128 * 128];
  __shared__ unsigned short B_s[128 * 128];
  int m0 = blockIdx.y * 128;
  int n0 = blockIdx.x * 128;
  int tid = threadIdx.x;

#pragma unroll
  for (int it = 0; it < 8; ++it) {
    int lin = it * 256 + tid;
    int row = lin >> 4, slot = lin & 15;
    int sw = slot ^ (row & 7);
    uint4 va = *(const uint4*)(A + ((size_t)(m0 + row)) * 128 + slot * 8);
    *(uint4*)(A_s + row * 128 + sw * 8) = va;
    uint4 vb = *(const uint4*)(Bm + ((size_t)(n0 + row)) * 128 + slot * 8);
    *(uint4*)(B_s + row * 128 + sw * 8) = vb;
  }
  __syncthreads();

  int lane = tid & 63;
  int w = tid >> 6;
  int wm = (w >> 1) * 64, wn = (w & 1) * 64;
  int lr = lane & 15, g = lane >> 4;

  v4f acc[4][4];
#pragma unroll
  for (int mf = 0; mf < 4; ++mf)
#pragma unroll
    for (int nf = 0; nf < 4; ++nf) {
      v4f z = {0.f, 0.f, 0.f, 0.f};
      acc[mf][nf] = z;
    }

#pragma unroll
  for (int ks = 0; ks < 4; ++ks) {
    int kg = ks * 4 + g;
    v8s a[4], bfr[4];
#pragma unroll
    for (int mf = 0; mf < 4; ++mf) {
      int row = wm + mf * 16 + lr;
      a[mf] = *(v8s*)(A_s + row * 128 + ((kg ^ (row & 7)) * 8));
    }
#pragma unroll
    for (int nf = 0; nf < 4; ++nf) {
      int row = wn + nf * 16 + lr;
      bfr[nf] = *(v8s*)(B_s + row * 128 + ((kg ^ (row & 7)) * 8));
    }
#pragma unroll
    for (int mf = 0; mf < 4; ++mf)
#pragma unroll
      for (int nf = 0; nf < 4; ++nf)
        acc[mf][nf] = __builtin_amdgcn_mfma_f32_16x16x32_bf16(a[mf], bfr[nf], acc[mf][nf], 0, 0, 0);
  }

  // store: per (mf,reg): 4 nf stores cover 256B contiguous per 16-lane group
  int mbase = m0 + wm + g * 4;
  int nbase = n0 + wn + lr;
#pragma unroll
  for (int mf = 0; mf < 4; ++mf) {
#pragma unroll
    for (int reg = 0; reg < 4; ++reg) {
      int m = mbase + mf * 16 + reg;
      float* crow = Cc + (size_t)m * QQ;
#pragma unroll
      for (int nf = 0; nf < 4; ++nf) {
        int n = nbase + nf * 16;
        if (n < QQ) crow[n] = acc[mf][nf][reg];
      }
    }
  }
}

// ---------------------------------------------------------------------------
extern "C" void kernel_launch(void* const* d_in, const int* in_sizes, int n_in,
                              void* d_out, int out_size, void* d_ws, size_t ws_size,
                              hipStream_t stream) {
  (void)in_sizes; (void)n_in; (void)out_size; (void)ws_size;
  const int*   idx   = (const int*)d_in[0];
  const float* preW  = (const float*)d_in[1];
  const float* filtW = (const float*)d_in[2];
  const float* gateW = (const float*)d_in[3];
  const float* resW  = (const float*)d_in[4];
  const float* skipW = (const float*)d_in[5];
  const float* W1    = (const float*)d_in[6];
  const float* W2    = (const float*)d_in[7];
  float* out = (float*)d_out;

  char* ws = (char*)d_ws;
  float* x_a = (float*)(ws);                               //   786,432 B
  float* x_b = (float*)(ws + 786432);                      //   786,432 B
  float* skip = (float*)(ws + 1572864);                    // 3,670,016 B
  unsigned short* h1  = (unsigned short*)(ws + 5242880);   // 1,835,008 B
  unsigned short* W2T = (unsigned short*)(ws + 7077888);   // 4,194,304 B  (total ~11.3 MB)

  hipMemsetAsync(skip, 0, (size_t)BB * OUTW * SS * sizeof(float), stream);

  embed_kernel<<<dim3((BB * (LL - 1) + 255) / 256), 256, 0, stream>>>(idx, preW, x_a);
  w2t_kernel<<<dim3(NPAD / 64), 256, 0, stream>>>(W2, W2T);

  const float* xi = x_a;
  float* xo = x_b;
  for (int i = 0; i < NLAYER; ++i) {
    int Tout = (TT0 - i) - 1;  // 2046 - i
    dim3 grid((Tout + 63) / 64, BB);
    layer_kernel<<<grid, 256, 0, stream>>>(xi, xo, skip, filtW, gateW, resW, skipW, i, Tout);
    float* tmp = (float*)xi;
    xi = xo;
    xo = tmp;
  }

  h1_kernel<<<dim3(MROWS / 64), 256, 0, stream>>>(skip, W1, h1);
  gemm_kernel<<<dim3(NPAD / 128, MROWS / 128), 256, 0, stream>>>(h1, W2T, out);
}

// Round 2
// 442.960 us; speedup vs baseline: 1.6005x; 1.6005x over previous
//
#include <hip/hip_runtime.h>
#include <stdint.h>

// Problem constants
#define BB 4
#define LL 2048
#define QQ 16293
#define RR 24
#define DD 32
#define SS 128
#define NLAYER 8
#define OUTW 1792
#define TT0 2047              // length of x after embedding (L-1)
#define MROWS (BB*OUTW)       // 7168
#define NPAD 16384            // padded Q for GEMM tiles
#define WCH 56                // skip rows per fused-layer block (32 chunks exactly)

typedef float v4f __attribute__((ext_vector_type(4)));
typedef short v8s __attribute__((ext_vector_type(8)));

static __device__ __forceinline__ unsigned short f2bf(float x) {
  unsigned int u = __float_as_uint(x);
  unsigned int r = (u + 0x7fffu + ((u >> 16) & 1u)) >> 16;
  return (unsigned short)r;
}

static __device__ __forceinline__ float fast_sigmoid(float z) {
  return __builtin_amdgcn_rcpf(1.0f + __expf(-z));
}
static __device__ __forceinline__ float fast_tanh(float z) {
  // tanh(z) = 1 - 2/(1+e^{2z}); graceful at |z| large (exp->inf -> rcp->0)
  return 1.0f - 2.0f * __builtin_amdgcn_rcpf(1.0f + __expf(2.0f * z));
}

// ---------------------------------------------------------------------------
// Fused: embedding + 8 WaveNet layers + skip accumulation.
// Grid (32, B), block 256 = 4 waves. Block covers skip rows [j0, j0+56).
// Receptive halo = 8, so 64 x-positions (t = j0+247+lane) suffice for the
// whole chain. x lives in LDS column-major [r][66] double-buffered; out
// exchanged via [64][33]; skip accumulated in 32 VGPRs per thread
// (lane = skip row j, wave w = s-slice [32w,32w+32)).
// Layer i: out_i valid at lanes l in [0, 62-i]; skip row j takes
// out_i[l = j+7-i]; x_{i+1}[l] = x_i[l+1] + out_i[l] @ res_W.
// Weight indices are wave-uniform -> s_load + SGPR-operand v_fmac.
// ---------------------------------------------------------------------------
__global__ __launch_bounds__(256) void fused_layers_kernel(
    const int* __restrict__ idx, const float* __restrict__ preW,
    const float* __restrict__ filtW, const float* __restrict__ gateW,
    const float* __restrict__ resW, const float* __restrict__ skipW,
    float* __restrict__ skip_out) {
  int b = blockIdx.y;
  int j0 = blockIdx.x * WCH;
  int lane = (int)(threadIdx.x & 63);
  int w = __builtin_amdgcn_readfirstlane((int)(threadIdx.x >> 6));

  __shared__ float x_t[2][RR][66];   // col-major: x_t[buf][r][l]
  __shared__ float out_s[64][33];

  int tbase = j0 + 247;

  // ---- embedding: x_0 at lanes 0..63, each wave fills r-slice [6w,6w+6)
  {
    int t = tbase + lane;            // t <= 1736+247+63 = 2046
    int i0 = idx[b * LL + t];
    int i1 = idx[b * LL + t + 1];
    const float2* p0 = (const float2*)(preW + (size_t)i0 * RR + 6 * w);
    const float2* p1 = (const float2*)(preW + (size_t)QQ * RR + (size_t)i1 * RR + 6 * w);
#pragma unroll
    for (int rr = 0; rr < 3; ++rr) {
      float2 a = p0[rr];
      float2 c = p1[rr];
      x_t[0][6 * w + 2 * rr + 0][lane] = a.x + c.x;
      x_t[0][6 * w + 2 * rr + 1][lane] = a.y + c.y;
    }
  }

  float sk[32];
#pragma unroll
  for (int c = 0; c < 32; ++c) sk[c] = 0.f;

  __syncthreads();

  for (int i = 0; i < NLAYER; ++i) {
    int cur = i & 1, nxt = cur ^ 1;
    int lmax = 62 - i;               // out_i valid at lanes [0, lmax]

    // ---- conv phase: every thread reads full x rows (lane, lane+1)
    float xa[RR], xb[RR];
#pragma unroll
    for (int r = 0; r < RR; ++r) {
      xa[r] = x_t[cur][r][lane];
      xb[r] = x_t[cur][r][lane + 1];  // col 64 exists (garbage ok, masked)
    }
    const float* Fw = filtW + (size_t)i * 2 * RR * DD;
    const float* Gw = gateW + (size_t)i * 2 * RR * DD;
    float zf[8], zg[8];
#pragma unroll
    for (int dd = 0; dd < 8; ++dd) { zf[dd] = 0.f; zg[dd] = 0.f; }
#pragma unroll
    for (int r = 0; r < RR; ++r) {
#pragma unroll
      for (int dd = 0; dd < 8; ++dd) {
        int d = w * 8 + dd;
        zf[dd] = fmaf(xa[r], Fw[r * DD + d], zf[dd]);
        zf[dd] = fmaf(xb[r], Fw[RR * DD + r * DD + d], zf[dd]);
        zg[dd] = fmaf(xa[r], Gw[r * DD + d], zg[dd]);
        zg[dd] = fmaf(xb[r], Gw[RR * DD + r * DD + d], zg[dd]);
      }
    }
    if (lane <= lmax) {
#pragma unroll
      for (int dd = 0; dd < 8; ++dd)
        out_s[lane][w * 8 + dd] = fast_tanh(zf[dd]) * fast_sigmoid(zg[dd]);
    }
    __syncthreads();

    // ---- skip phase: lane = skip row j, reads out row j+7-i
    if (lane < WCH) {
      const float* Sw = skipW + (size_t)i * DD * SS + w * 32;
#pragma unroll
      for (int d = 0; d < DD; ++d) {
        float o = out_s[lane + 7 - i][d];
#pragma unroll
        for (int c = 0; c < 32; ++c)
          sk[c] = fmaf(o, Sw[d * SS + c], sk[c]);
      }
    }

    // ---- residual phase: x_{i+1}[l] = x_i[l+1] + out_i[l] @ res_W (r-slice)
    if (lane <= lmax) {
      const float* Rw = resW + (size_t)i * DD * RR;
#pragma unroll
      for (int rr = 0; rr < 6; ++rr) {
        int r = w * 6 + rr;
        float acc = x_t[cur][r][lane + 1];
#pragma unroll
        for (int d = 0; d < DD; ++d)
          acc = fmaf(out_s[lane][d], Rw[d * RR + r], acc);
        x_t[nxt][r][lane] = acc;
      }
    }
    __syncthreads();
  }

  // ---- write skip_sum
  if (lane < WCH) {
    float* sp = skip_out + ((size_t)b * OUTW + j0 + lane) * SS + w * 32;
#pragma unroll
    for (int c4 = 0; c4 < 8; ++c4) {
      float4 v;
      v.x = sk[4 * c4 + 0]; v.y = sk[4 * c4 + 1];
      v.z = sk[4 * c4 + 2]; v.w = sk[4 * c4 + 3];
      *(float4*)(sp + 4 * c4) = v;
    }
  }
}

// ---------------------------------------------------------------------------
// h1 = relu(relu(skip_sum) @ post_W1), stored bf16  [7168][128]  (unchanged)
// ---------------------------------------------------------------------------
__global__ __launch_bounds__(256) void h1_kernel(const float* __restrict__ skip_sum,
                                                 const float* __restrict__ W1,
                                                 unsigned short* __restrict__ h1) {
  int m0 = blockIdx.x * 64;
  int tc = threadIdx.x & 31;
  int tr = threadIdx.x >> 5;
  __shared__ float h_s[64][128];
#pragma unroll
  for (int it = 0; it < 32; ++it) {
    int lin = it * 256 + (int)threadIdx.x;
    int rrow = lin >> 7, d = lin & 127;
    float v = skip_sum[(size_t)(m0 + rrow) * SS + d];
    h_s[rrow][d] = v > 0.f ? v : 0.f;
  }
  __syncthreads();

  float acc[8][4];
#pragma unroll
  for (int rr = 0; rr < 8; ++rr)
#pragma unroll
    for (int c = 0; c < 4; ++c) acc[rr][c] = 0.f;

#pragma unroll 4
  for (int d = 0; d < 128; ++d) {
    float4 wv = *(const float4*)(W1 + (size_t)d * SS + tc * 4);
#pragma unroll
    for (int rr = 0; rr < 8; ++rr) {
      float hv = h_s[tr * 8 + rr][d];
      acc[rr][0] = fmaf(hv, wv.x, acc[rr][0]);
      acc[rr][1] = fmaf(hv, wv.y, acc[rr][1]);
      acc[rr][2] = fmaf(hv, wv.z, acc[rr][2]);
      acc[rr][3] = fmaf(hv, wv.w, acc[rr][3]);
    }
  }
#pragma unroll
  for (int rr = 0; rr < 8; ++rr) {
    int row = m0 + tr * 8 + rr;
    ushort4 u;
    u.x = f2bf(fmaxf(acc[rr][0], 0.f));
    u.y = f2bf(fmaxf(acc[rr][1], 0.f));
    u.z = f2bf(fmaxf(acc[rr][2], 0.f));
    u.w = f2bf(fmaxf(acc[rr][3], 0.f));
    *(ushort4*)(h1 + (size_t)row * SS + tc * 4) = u;
  }
}

// ---------------------------------------------------------------------------
// W2T: transpose post_W2 [128][16293] -> bf16 [16384][128], zero-padded
// ---------------------------------------------------------------------------
__global__ __launch_bounds__(256) void w2t_kernel(const float* __restrict__ W2,
                                                  unsigned short* __restrict__ W2T) {
  int n0 = blockIdx.x * 64;
  __shared__ float t_s[64][129];
#pragma unroll
  for (int it = 0; it < 32; ++it) {
    int lin = it * 256 + (int)threadIdx.x;
    int k = lin >> 6, nn = lin & 63;
    int n = n0 + nn;
    t_s[nn][k] = (n < QQ) ? W2[(size_t)k * QQ + n] : 0.f;
  }
  __syncthreads();
#pragma unroll
  for (int it = 0; it < 4; ++it) {
    int lin = it * 256 + (int)threadIdx.x;
    int nn = lin >> 4, slot = lin & 15;
    v8s val;
#pragma unroll
    for (int jj = 0; jj < 8; ++jj) val[jj] = (short)f2bf(t_s[nn][slot * 8 + jj]);
    *(v8s*)(W2T + ((size_t)(n0 + nn)) * 128 + slot * 8) = val;
  }
}

// ---------------------------------------------------------------------------
// logits = h1 @ W2  (bf16 MFMA, fp32 accum).  (unchanged)
// ---------------------------------------------------------------------------
__global__ __launch_bounds__(256) void gemm_kernel(const unsigned short* __restrict__ A,
                                                   const unsigned short* __restrict__ Bm,
                                                   float* __restrict__ Cc) {
  __shared__ unsigned short A_s[128 * 128];
  __shared__ unsigned short B_s[128 * 128];
  int m0 = blockIdx.y * 128;
  int n0 = blockIdx.x * 128;
  int tid = threadIdx.x;

#pragma unroll
  for (int it = 0; it < 8; ++it) {
    int lin = it * 256 + tid;
    int row = lin >> 4, slot = lin & 15;
    int sw = slot ^ (row & 7);
    uint4 va = *(const uint4*)(A + ((size_t)(m0 + row)) * 128 + slot * 8);
    *(uint4*)(A_s + row * 128 + sw * 8) = va;
    uint4 vb = *(const uint4*)(Bm + ((size_t)(n0 + row)) * 128 + slot * 8);
    *(uint4*)(B_s + row * 128 + sw * 8) = vb;
  }
  __syncthreads();

  int lane = tid & 63;
  int w = tid >> 6;
  int wm = (w >> 1) * 64, wn = (w & 1) * 64;
  int lr = lane & 15, g = lane >> 4;

  v4f acc[4][4];
#pragma unroll
  for (int mf = 0; mf < 4; ++mf)
#pragma unroll
    for (int nf = 0; nf < 4; ++nf) {
      v4f z = {0.f, 0.f, 0.f, 0.f};
      acc[mf][nf] = z;
    }

#pragma unroll
  for (int ks = 0; ks < 4; ++ks) {
    int kg = ks * 4 + g;
    v8s a[4], bfr[4];
#pragma unroll
    for (int mf = 0; mf < 4; ++mf) {
      int row = wm + mf * 16 + lr;
      a[mf] = *(v8s*)(A_s + row * 128 + ((kg ^ (row & 7)) * 8));
    }
#pragma unroll
    for (int nf = 0; nf < 4; ++nf) {
      int row = wn + nf * 16 + lr;
      bfr[nf] = *(v8s*)(B_s + row * 128 + ((kg ^ (row & 7)) * 8));
    }
#pragma unroll
    for (int mf = 0; mf < 4; ++mf)
#pragma unroll
      for (int nf = 0; nf < 4; ++nf)
        acc[mf][nf] = __builtin_amdgcn_mfma_f32_16x16x32_bf16(a[mf], bfr[nf], acc[mf][nf], 0, 0, 0);
  }

  int mbase = m0 + wm + g * 4;
  int nbase = n0 + wn + lr;
#pragma unroll
  for (int mf = 0; mf < 4; ++mf) {
#pragma unroll
    for (int reg = 0; reg < 4; ++reg) {
      int m = mbase + mf * 16 + reg;
      float* crow = Cc + (size_t)m * QQ;
#pragma unroll
      for (int nf = 0; nf < 4; ++nf) {
        int n = nbase + nf * 16;
        if (n < QQ) crow[n] = acc[mf][nf][reg];
      }
    }
  }
}

// ---------------------------------------------------------------------------
extern "C" void kernel_launch(void* const* d_in, const int* in_sizes, int n_in,
                              void* d_out, int out_size, void* d_ws, size_t ws_size,
                              hipStream_t stream) {
  (void)in_sizes; (void)n_in; (void)out_size; (void)ws_size;
  const int*   idx   = (const int*)d_in[0];
  const float* preW  = (const float*)d_in[1];
  const float* filtW = (const float*)d_in[2];
  const float* gateW = (const float*)d_in[3];
  const float* resW  = (const float*)d_in[4];
  const float* skipW = (const float*)d_in[5];
  const float* W1    = (const float*)d_in[6];
  const float* W2    = (const float*)d_in[7];
  float* out = (float*)d_out;

  char* ws = (char*)d_ws;
  float* skip = (float*)(ws);                              // 3,670,016 B
  unsigned short* h1  = (unsigned short*)(ws + 3670016);   // 1,835,008 B
  unsigned short* W2T = (unsigned short*)(ws + 5505024);   // 4,194,304 B  (~9.7 MB)

  w2t_kernel<<<dim3(NPAD / 64), 256, 0, stream>>>(W2, W2T);
  fused_layers_kernel<<<dim3(OUTW / WCH, BB), 256, 0, stream>>>(idx, preW, filtW, gateW,
                                                                resW, skipW, skip);
  h1_kernel<<<dim3(MROWS / 64), 256, 0, stream>>>(skip, W1, h1);
  gemm_kernel<<<dim3(NPAD / 128, MROWS / 128), 256, 0, stream>>>(h1, W2T, out);
}

// Round 4
// 278.187 us; speedup vs baseline: 2.5485x; 1.5923x over previous
//
#include <hip/hip_runtime.h>
#include <stdint.h>

// Problem constants
#define BB 4
#define LL 2048
#define QQ 16293
#define RR 24
#define DD 32
#define SS 128
#define NLAYER 8
#define OUTW 1792
#define TT0 2047              // length of x after embedding (L-1)
#define MROWS (BB*OUTW)       // 7168
#define NPAD 16384            // padded Q for GEMM tiles
#define WCH 28                // skip rows per fused-layer block (64 blocks/batch)

typedef float v4f __attribute__((ext_vector_type(4)));
typedef short v8s __attribute__((ext_vector_type(8)));

static __device__ __forceinline__ unsigned short f2bf(float x) {
  unsigned int u = __float_as_uint(x);
  unsigned int r = (u + 0x7fffu + ((u >> 16) & 1u)) >> 16;
  return (unsigned short)r;
}

static __device__ __forceinline__ float fast_sigmoid(float z) {
  return __builtin_amdgcn_rcpf(1.0f + __expf(-z));
}
static __device__ __forceinline__ float fast_tanh(float z) {
  return 1.0f - 2.0f * __builtin_amdgcn_rcpf(1.0f + __expf(2.0f * z));
}

// ---------------------------------------------------------------------------
// Fused: embedding + 8 WaveNet layers + skip accumulation.
// Grid (64, B), block 512 = 8 waves, 2 waves/SIMD (s_load stall overlap).
// Block covers skip rows [j0, j0+28). Receptive halo = 8 -> 36 x-positions
// needed; 64 lanes computed (waste accepted for uniform code).
// Wave w of 8 owns: conv d-slice [4w,4w+4), skip c-slice [16w,16w+16),
// residual r-slice [3w,3w+3), embed r-slice [3w,3w+3).
// x in LDS column-major [r][66] double-buffered (conflict-free per-lane cols);
// out exchanged via [64][33]; skip accumulated in 16 VGPRs/thread.
// Weight indices are wave-uniform -> s_load + SGPR-operand v_fmac.
// ---------------------------------------------------------------------------
__global__ __launch_bounds__(512) void fused_layers_kernel(
    const int* __restrict__ idx, const float* __restrict__ preW,
    const float* __restrict__ filtW, const float* __restrict__ gateW,
    const float* __restrict__ resW, const float* __restrict__ skipW,
    float* __restrict__ skip_out) {
  int b = blockIdx.y;
  int j0 = blockIdx.x * WCH;
  int lane = (int)(threadIdx.x & 63);
  int w = __builtin_amdgcn_readfirstlane((int)(threadIdx.x >> 6));

  __shared__ float x_t[2][RR][66];   // col-major: x_t[buf][r][l]
  __shared__ float out_s[64][33];

  // zero the halo columns 64,65 of both buffers (avoid uninitialized reads)
  for (int z = (int)threadIdx.x; z < 2 * RR * 2; z += 512) {
    int bu = z & 1;
    int cc = 64 + ((z >> 1) & 1);
    int r = z >> 2;
    x_t[bu][r][cc] = 0.f;
  }

  int tbase = j0 + 247;
  // ---- embedding: x_0 at lanes 0..63, wave fills r-slice [3w,3w+3)
  {
    int t = tbase + lane;
    if (t > TT0 - 1) t = TT0 - 1;    // clamp (garbage lanes masked downstream)
    int i0 = idx[b * LL + t];
    int i1 = idx[b * LL + t + 1];
    const float* p0 = preW + (size_t)i0 * RR + 3 * w;
    const float* p1 = preW + (size_t)QQ * RR + (size_t)i1 * RR + 3 * w;
#pragma unroll
    for (int rr = 0; rr < 3; ++rr)
      x_t[0][3 * w + rr][lane] = p0[rr] + p1[rr];
  }

  float sk[16];
#pragma unroll
  for (int c = 0; c < 16; ++c) sk[c] = 0.f;

  __syncthreads();

  for (int i = 0; i < NLAYER; ++i) {
    int cur = i & 1, nxt = cur ^ 1;
    int lmax = 62 - i;               // out_i valid at lanes [0, lmax]

    // ---- conv phase: thread reads full x rows (lane, lane+1), d-slice of 4
    float xa[RR], xb[RR];
#pragma unroll
    for (int r = 0; r < RR; ++r) {
      xa[r] = x_t[cur][r][lane];
      xb[r] = x_t[cur][r][lane + 1];
    }
    const float* Fw = filtW + (size_t)i * 2 * RR * DD;
    const float* Gw = gateW + (size_t)i * 2 * RR * DD;
    float zf[4], zg[4];
#pragma unroll
    for (int dd = 0; dd < 4; ++dd) { zf[dd] = 0.f; zg[dd] = 0.f; }
#pragma unroll
    for (int r = 0; r < RR; ++r) {
#pragma unroll
      for (int dd = 0; dd < 4; ++dd) {
        int d = w * 4 + dd;
        zf[dd] = fmaf(xa[r], Fw[r * DD + d], zf[dd]);
        zf[dd] = fmaf(xb[r], Fw[RR * DD + r * DD + d], zf[dd]);
        zg[dd] = fmaf(xa[r], Gw[r * DD + d], zg[dd]);
        zg[dd] = fmaf(xb[r], Gw[RR * DD + r * DD + d], zg[dd]);
      }
    }
    if (lane <= lmax) {
#pragma unroll
      for (int dd = 0; dd < 4; ++dd)
        out_s[lane][w * 4 + dd] = fast_tanh(zf[dd]) * fast_sigmoid(zg[dd]);
    }
    __syncthreads();

    // ---- skip phase: lane = skip row j, reads out row lane+7-i, c-slice 16
    if (lane < WCH) {
      const float* Sw = skipW + (size_t)i * DD * SS + w * 16;
#pragma unroll
      for (int d = 0; d < DD; ++d) {
        float o = out_s[lane + 7 - i][d];
#pragma unroll
        for (int c = 0; c < 16; ++c)
          sk[c] = fmaf(o, Sw[d * SS + c], sk[c]);
      }
    }

    // ---- residual phase: x_{i+1}[l] = x_i[l+1] + out_i[l] @ res_W, r-slice 3
    if (lane <= lmax) {
      const float* Rw = resW + (size_t)i * DD * RR;
#pragma unroll
      for (int rr = 0; rr < 3; ++rr) {
        int r = w * 3 + rr;
        float acc = x_t[cur][r][lane + 1];
#pragma unroll
        for (int d = 0; d < DD; ++d)
          acc = fmaf(out_s[lane][d], Rw[d * RR + r], acc);
        x_t[nxt][r][lane] = acc;
      }
    }
    __syncthreads();
  }

  // ---- write skip_sum (wave w covers cols [16w,16w+16))
  if (lane < WCH) {
    float* sp = skip_out + ((size_t)b * OUTW + j0 + lane) * SS + w * 16;
#pragma unroll
    for (int c4 = 0; c4 < 4; ++c4) {
      float4 v;
      v.x = sk[4 * c4 + 0]; v.y = sk[4 * c4 + 1];
      v.z = sk[4 * c4 + 2]; v.w = sk[4 * c4 + 3];
      *(float4*)(sp + 4 * c4) = v;
    }
  }
}

// ---------------------------------------------------------------------------
// h1 = relu(relu(skip_sum) @ post_W1), stored bf16  [7168][128]
// ---------------------------------------------------------------------------
__global__ __launch_bounds__(256) void h1_kernel(const float* __restrict__ skip_sum,
                                                 const float* __restrict__ W1,
                                                 unsigned short* __restrict__ h1) {
  int m0 = blockIdx.x * 64;
  int tc = threadIdx.x & 31;
  int tr = threadIdx.x >> 5;
  __shared__ float h_s[64][128];
#pragma unroll
  for (int it = 0; it < 32; ++it) {
    int lin = it * 256 + (int)threadIdx.x;
    int rrow = lin >> 7, d = lin & 127;
    float v = skip_sum[(size_t)(m0 + rrow) * SS + d];
    h_s[rrow][d] = v > 0.f ? v : 0.f;
  }
  __syncthreads();

  float acc[8][4];
#pragma unroll
  for (int rr = 0; rr < 8; ++rr)
#pragma unroll
    for (int c = 0; c < 4; ++c) acc[rr][c] = 0.f;

#pragma unroll 4
  for (int d = 0; d < 128; ++d) {
    float4 wv = *(const float4*)(W1 + (size_t)d * SS + tc * 4);
#pragma unroll
    for (int rr = 0; rr < 8; ++rr) {
      float hv = h_s[tr * 8 + rr][d];
      acc[rr][0] = fmaf(hv, wv.x, acc[rr][0]);
      acc[rr][1] = fmaf(hv, wv.y, acc[rr][1]);
      acc[rr][2] = fmaf(hv, wv.z, acc[rr][2]);
      acc[rr][3] = fmaf(hv, wv.w, acc[rr][3]);
    }
  }
#pragma unroll
  for (int rr = 0; rr < 8; ++rr) {
    int row = m0 + tr * 8 + rr;
    ushort4 u;
    u.x = f2bf(fmaxf(acc[rr][0], 0.f));
    u.y = f2bf(fmaxf(acc[rr][1], 0.f));
    u.z = f2bf(fmaxf(acc[rr][2], 0.f));
    u.w = f2bf(fmaxf(acc[rr][3], 0.f));
    *(ushort4*)(h1 + (size_t)row * SS + tc * 4) = u;
  }
}

// ---------------------------------------------------------------------------
// W2T: transpose post_W2 [128][16293] -> bf16 [16384][128], zero-padded
// ---------------------------------------------------------------------------
__global__ __launch_bounds__(256) void w2t_kernel(const float* __restrict__ W2,
                                                  unsigned short* __restrict__ W2T) {
  int n0 = blockIdx.x * 64;
  __shared__ float t_s[64][129];
#pragma unroll
  for (int it = 0; it < 32; ++it) {
    int lin = it * 256 + (int)threadIdx.x;
    int k = lin >> 6, nn = lin & 63;
    int n = n0 + nn;
    t_s[nn][k] = (n < QQ) ? W2[(size_t)k * QQ + n] : 0.f;
  }
  __syncthreads();
#pragma unroll
  for (int it = 0; it < 4; ++it) {
    int lin = it * 256 + (int)threadIdx.x;
    int nn = lin >> 4, slot = lin & 15;
    v8s val;
#pragma unroll
    for (int jj = 0; jj < 8; ++jj) val[jj] = (short)f2bf(t_s[nn][slot * 8 + jj]);
    *(v8s*)(W2T + ((size_t)(n0 + nn)) * 128 + slot * 8) = val;
  }
}

// ---------------------------------------------------------------------------
// logits = h1 @ W2  (bf16 MFMA, fp32 accum).  M=7168, N=16384(pad), K=128.
// Epilogue: C tile through LDS [128][132] (pad -> conflict-free), then
// fully-coalesced v4f nontemporal stores (512B per 32-lane group).
// ---------------------------------------------------------------------------
struct GemmLds {
  union {
    struct { unsigned short A_s[128 * 128]; unsigned short B_s[128 * 128]; } ab;
    float c_s[128][132];
  };
};

__global__ __launch_bounds__(256) void gemm_kernel(const unsigned short* __restrict__ A,
                                                   const unsigned short* __restrict__ Bm,
                                                   float* __restrict__ Cc) {
  __shared__ GemmLds sh;
  unsigned short* A_s = sh.ab.A_s;
  unsigned short* B_s = sh.ab.B_s;
  int m0 = blockIdx.y * 128;
  int n0 = blockIdx.x * 128;
  int tid = threadIdx.x;

#pragma unroll
  for (int it = 0; it < 8; ++it) {
    int lin = it * 256 + tid;
    int row = lin >> 4, slot = lin & 15;
    int sw = slot ^ (row & 7);
    uint4 va = *(const uint4*)(A + ((size_t)(m0 + row)) * 128 + slot * 8);
    *(uint4*)(A_s + row * 128 + sw * 8) = va;
    uint4 vb = *(const uint4*)(Bm + ((size_t)(n0 + row)) * 128 + slot * 8);
    *(uint4*)(B_s + row * 128 + sw * 8) = vb;
  }
  __syncthreads();

  int lane = tid & 63;
  int w = tid >> 6;
  int wm = (w >> 1) * 64, wn = (w & 1) * 64;
  int lr = lane & 15, g = lane >> 4;

  v4f acc[4][4];
#pragma unroll
  for (int mf = 0; mf < 4; ++mf)
#pragma unroll
    for (int nf = 0; nf < 4; ++nf) {
      v4f z = {0.f, 0.f, 0.f, 0.f};
      acc[mf][nf] = z;
    }

#pragma unroll
  for (int ks = 0; ks < 4; ++ks) {
    int kg = ks * 4 + g;
    v8s a[4], bfr[4];
#pragma unroll
    for (int mf = 0; mf < 4; ++mf) {
      int row = wm + mf * 16 + lr;
      a[mf] = *(v8s*)(A_s + row * 128 + ((kg ^ (row & 7)) * 8));
    }
#pragma unroll
    for (int nf = 0; nf < 4; ++nf) {
      int row = wn + nf * 16 + lr;
      bfr[nf] = *(v8s*)(B_s + row * 128 + ((kg ^ (row & 7)) * 8));
    }
#pragma unroll
    for (int mf = 0; mf < 4; ++mf)
#pragma unroll
      for (int nf = 0; nf < 4; ++nf)
        acc[mf][nf] = __builtin_amdgcn_mfma_f32_16x16x32_bf16(a[mf], bfr[nf], acc[mf][nf], 0, 0, 0);
  }

  // ---- epilogue: acc -> LDS (conflict-light), then coalesced nt stores
  __syncthreads();   // all LDS reads of A_s/B_s done
#pragma unroll
  for (int mf = 0; mf < 4; ++mf)
#pragma unroll
    for (int reg = 0; reg < 4; ++reg) {
      int row = wm + mf * 16 + g * 4 + reg;
#pragma unroll
      for (int nf = 0; nf < 4; ++nf)
        sh.c_s[row][wn + nf * 16 + lr] = acc[mf][nf][reg];
    }
  __syncthreads();

  int slot = tid & 31;            // 32 v4f-slots per 128-col row
  int rsub = tid >> 5;            // 8 rows per iteration
  bool edge = (n0 + 128 > QQ);
#pragma unroll
  for (int it = 0; it < 16; ++it) {
    int row = it * 8 + rsub;
    int n = n0 + slot * 4;
    v4f v = *(v4f*)(&sh.c_s[row][slot * 4]);
    float* crow = Cc + (size_t)(m0 + row) * QQ;
    if (!edge) {
      __builtin_nontemporal_store(v, (v4f*)(crow + n));
    } else {
      if (n + 3 < QQ) {
        __builtin_nontemporal_store(v, (v4f*)(crow + n));
      } else {
        if (n + 0 < QQ) crow[n + 0] = v.x;
        if (n + 1 < QQ) crow[n + 1] = v.y;
        if (n + 2 < QQ) crow[n + 2] = v.z;
        if (n + 3 < QQ) crow[n + 3] = v.w;
      }
    }
  }
}

// ---------------------------------------------------------------------------
extern "C" void kernel_launch(void* const* d_in, const int* in_sizes, int n_in,
                              void* d_out, int out_size, void* d_ws, size_t ws_size,
                              hipStream_t stream) {
  (void)in_sizes; (void)n_in; (void)out_size; (void)ws_size;
  const int*   idx   = (const int*)d_in[0];
  const float* preW  = (const float*)d_in[1];
  const float* filtW = (const float*)d_in[2];
  const float* gateW = (const float*)d_in[3];
  const float* resW  = (const float*)d_in[4];
  const float* skipW = (const float*)d_in[5];
  const float* W1    = (const float*)d_in[6];
  const float* W2    = (const float*)d_in[7];
  float* out = (float*)d_out;

  char* ws = (char*)d_ws;
  float* skip = (float*)(ws);                              // 3,670,016 B
  unsigned short* h1  = (unsigned short*)(ws + 3670016);   // 1,835,008 B
  unsigned short* W2T = (unsigned short*)(ws + 5505024);   // 4,194,304 B  (~9.7 MB)

  w2t_kernel<<<dim3(NPAD / 64), 256, 0, stream>>>(W2, W2T);
  fused_layers_kernel<<<dim3(OUTW / WCH, BB), 512, 0, stream>>>(idx, preW, filtW, gateW,
                                                                resW, skipW, skip);
  h1_kernel<<<dim3(MROWS / 64), 256, 0, stream>>>(skip, W1, h1);
  gemm_kernel<<<dim3(NPAD / 128, MROWS / 128), 256, 0, stream>>>(h1, W2T, out);
}

// Round 5
// 272.733 us; speedup vs baseline: 2.5994x; 1.0200x over previous
//
#include <hip/hip_runtime.h>
#include <stdint.h>

// Problem constants
#define BB 4
#define LL 2048
#define QQ 16293
#define RR 24
#define DD 32
#define SS 128
#define NLAYER 8
#define OUTW 1792
#define TT0 2047              // length of x after embedding (L-1)
#define MROWS (BB*OUTW)       // 7168
#define NPAD 16384            // padded Q for GEMM tiles
#define WCH 28                // skip rows per fused-layer block (64 blocks/batch)

typedef float v4f __attribute__((ext_vector_type(4)));
typedef short v8s __attribute__((ext_vector_type(8)));

static __device__ __forceinline__ unsigned short f2bf(float x) {
  unsigned int u = __float_as_uint(x);
  unsigned int r = (u + 0x7fffu + ((u >> 16) & 1u)) >> 16;
  return (unsigned short)r;
}

static __device__ __forceinline__ float fast_sigmoid(float z) {
  return __builtin_amdgcn_rcpf(1.0f + __expf(-z));
}
static __device__ __forceinline__ float fast_tanh(float z) {
  return 1.0f - 2.0f * __builtin_amdgcn_rcpf(1.0f + __expf(2.0f * z));
}

// ---------------------------------------------------------------------------
// Fused: embedding + 8 WaveNet layers + skip accumulation.
// Grid (64, B), block 1024 = 16 waves -> 4 waves/SIMD (s_load stall overlap;
// per-CU VALU unchanged vs 8-wave version, work just sliced 2x finer).
// Block covers skip rows [j0, j0+28); halo 8 -> 36 x-positions needed,
// 64 lanes computed.
// Wave w of 16 owns: conv d-slice [2w,2w+2), skip c-slice [8w,8w+8),
// residual/embed r-slice [2w,2w+2) for w<12.
// x in LDS column-major [r][66] double-buffered; out via [64][33];
// skip accumulated in 8 VGPRs/thread.
// Weight indices wave-uniform -> s_load + SGPR-operand v_fmac.
// ---------------------------------------------------------------------------
__global__ __launch_bounds__(1024) void fused_layers_kernel(
    const int* __restrict__ idx, const float* __restrict__ preW,
    const float* __restrict__ filtW, const float* __restrict__ gateW,
    const float* __restrict__ resW, const float* __restrict__ skipW,
    float* __restrict__ skip_out) {
  int b = blockIdx.y;
  int j0 = blockIdx.x * WCH;
  int lane = (int)(threadIdx.x & 63);
  int w = __builtin_amdgcn_readfirstlane((int)(threadIdx.x >> 6));

  __shared__ float x_t[2][RR][66];   // col-major: x_t[buf][r][l]
  __shared__ float out_s[64][33];

  // zero the halo columns 64,65 of both buffers
  for (int z = (int)threadIdx.x; z < 2 * RR * 2; z += 1024) {
    int bu = z & 1;
    int cc = 64 + ((z >> 1) & 1);
    int r = z >> 2;
    x_t[bu][r][cc] = 0.f;
  }

  int tbase = j0 + 247;
  // ---- embedding: lanes 0..63; waves 0..11 fill r-slice [2w,2w+2)
  if (w < 12) {
    int t = tbase + lane;
    if (t > TT0 - 1) t = TT0 - 1;    // clamp (garbage lanes masked downstream)
    int i0 = idx[b * LL + t];
    int i1 = idx[b * LL + t + 1];
    const float* p0 = preW + (size_t)i0 * RR + 2 * w;
    const float* p1 = preW + (size_t)QQ * RR + (size_t)i1 * RR + 2 * w;
#pragma unroll
    for (int rr = 0; rr < 2; ++rr)
      x_t[0][2 * w + rr][lane] = p0[rr] + p1[rr];
  }

  float sk[8];
#pragma unroll
  for (int c = 0; c < 8; ++c) sk[c] = 0.f;

  __syncthreads();

  for (int i = 0; i < NLAYER; ++i) {
    int cur = i & 1, nxt = cur ^ 1;
    int lmax = 62 - i;               // out_i valid at lanes [0, lmax]

    // ---- conv phase: thread reads full x rows (lane, lane+1), d-slice of 2
    float xa[RR], xb[RR];
#pragma unroll
    for (int r = 0; r < RR; ++r) {
      xa[r] = x_t[cur][r][lane];
      xb[r] = x_t[cur][r][lane + 1];
    }
    const float* Fw = filtW + (size_t)i * 2 * RR * DD;
    const float* Gw = gateW + (size_t)i * 2 * RR * DD;
    float zf[2], zg[2];
#pragma unroll
    for (int dd = 0; dd < 2; ++dd) { zf[dd] = 0.f; zg[dd] = 0.f; }
#pragma unroll
    for (int r = 0; r < RR; ++r) {
#pragma unroll
      for (int dd = 0; dd < 2; ++dd) {
        int d = w * 2 + dd;
        zf[dd] = fmaf(xa[r], Fw[r * DD + d], zf[dd]);
        zf[dd] = fmaf(xb[r], Fw[RR * DD + r * DD + d], zf[dd]);
        zg[dd] = fmaf(xa[r], Gw[r * DD + d], zg[dd]);
        zg[dd] = fmaf(xb[r], Gw[RR * DD + r * DD + d], zg[dd]);
      }
    }
    if (lane <= lmax) {
#pragma unroll
      for (int dd = 0; dd < 2; ++dd)
        out_s[lane][w * 2 + dd] = fast_tanh(zf[dd]) * fast_sigmoid(zg[dd]);
    }
    __syncthreads();

    // ---- skip phase: lane = skip row j, reads out row lane+7-i, c-slice 8
    if (lane < WCH) {
      const float* Sw = skipW + (size_t)i * DD * SS + w * 8;
#pragma unroll
      for (int d = 0; d < DD; ++d) {
        float o = out_s[lane + 7 - i][d];
#pragma unroll
        for (int c = 0; c < 8; ++c)
          sk[c] = fmaf(o, Sw[d * SS + c], sk[c]);
      }
    }

    // ---- residual phase: x_{i+1}[l] = x_i[l+1] + out_i[l] @ res_W, r-slice 2
    if (w < 12 && lane <= lmax) {
      const float* Rw = resW + (size_t)i * DD * RR;
#pragma unroll
      for (int rr = 0; rr < 2; ++rr) {
        int r = w * 2 + rr;
        float acc = x_t[cur][r][lane + 1];
#pragma unroll
        for (int d = 0; d < DD; ++d)
          acc = fmaf(out_s[lane][d], Rw[d * RR + r], acc);
        x_t[nxt][r][lane] = acc;
      }
    }
    __syncthreads();
  }

  // ---- write skip_sum (wave w covers cols [8w,8w+8))
  if (lane < WCH) {
    float* sp = skip_out + ((size_t)b * OUTW + j0 + lane) * SS + w * 8;
#pragma unroll
    for (int c4 = 0; c4 < 2; ++c4) {
      float4 v;
      v.x = sk[4 * c4 + 0]; v.y = sk[4 * c4 + 1];
      v.z = sk[4 * c4 + 2]; v.w = sk[4 * c4 + 3];
      *(float4*)(sp + 4 * c4) = v;
    }
  }
}

// ---------------------------------------------------------------------------
// h1 = relu(relu(skip_sum) @ post_W1), stored bf16  [7168][128]
// 224 blocks x 32 rows (was 112 x 64 -- under half the GPU).
// ---------------------------------------------------------------------------
__global__ __launch_bounds__(256) void h1_kernel(const float* __restrict__ skip_sum,
                                                 const float* __restrict__ W1,
                                                 unsigned short* __restrict__ h1) {
  int m0 = blockIdx.x * 32;
  int tc = threadIdx.x & 31;
  int tr = threadIdx.x >> 5;
  __shared__ float h_s[32][128];
#pragma unroll
  for (int it = 0; it < 16; ++it) {
    int lin = it * 256 + (int)threadIdx.x;
    int rrow = lin >> 7, d = lin & 127;
    float v = skip_sum[(size_t)(m0 + rrow) * SS + d];
    h_s[rrow][d] = v > 0.f ? v : 0.f;
  }
  __syncthreads();

  float acc[4][4];
#pragma unroll
  for (int rr = 0; rr < 4; ++rr)
#pragma unroll
    for (int c = 0; c < 4; ++c) acc[rr][c] = 0.f;

#pragma unroll 4
  for (int d = 0; d < 128; ++d) {
    float4 wv = *(const float4*)(W1 + (size_t)d * SS + tc * 4);
#pragma unroll
    for (int rr = 0; rr < 4; ++rr) {
      float hv = h_s[tr * 4 + rr][d];
      acc[rr][0] = fmaf(hv, wv.x, acc[rr][0]);
      acc[rr][1] = fmaf(hv, wv.y, acc[rr][1]);
      acc[rr][2] = fmaf(hv, wv.z, acc[rr][2]);
      acc[rr][3] = fmaf(hv, wv.w, acc[rr][3]);
    }
  }
#pragma unroll
  for (int rr = 0; rr < 4; ++rr) {
    int row = m0 + tr * 4 + rr;
    ushort4 u;
    u.x = f2bf(fmaxf(acc[rr][0], 0.f));
    u.y = f2bf(fmaxf(acc[rr][1], 0.f));
    u.z = f2bf(fmaxf(acc[rr][2], 0.f));
    u.w = f2bf(fmaxf(acc[rr][3], 0.f));
    *(ushort4*)(h1 + (size_t)row * SS + tc * 4) = u;
  }
}

// ---------------------------------------------------------------------------
// W2T: transpose post_W2 [128][16293] -> bf16 [16384][128], zero-padded
// ---------------------------------------------------------------------------
__global__ __launch_bounds__(256) void w2t_kernel(const float* __restrict__ W2,
                                                  unsigned short* __restrict__ W2T) {
  int n0 = blockIdx.x * 64;
  __shared__ float t_s[64][129];
#pragma unroll
  for (int it = 0; it < 32; ++it) {
    int lin = it * 256 + (int)threadIdx.x;
    int k = lin >> 6, nn = lin & 63;
    int n = n0 + nn;
    t_s[nn][k] = (n < QQ) ? W2[(size_t)k * QQ + n] : 0.f;
  }
  __syncthreads();
#pragma unroll
  for (int it = 0; it < 4; ++it) {
    int lin = it * 256 + (int)threadIdx.x;
    int nn = lin >> 4, slot = lin & 15;
    v8s val;
#pragma unroll
    for (int jj = 0; jj < 8; ++jj) val[jj] = (short)f2bf(t_s[nn][slot * 8 + jj]);
    *(v8s*)(W2T + ((size_t)(n0 + nn)) * 128 + slot * 8) = val;
  }
}

// ---------------------------------------------------------------------------
// logits = h1 @ W2  (bf16 MFMA, fp32 accum).  M=7168, N=16384(pad), K=128.
// Epilogue: C tile through LDS [128][132], coalesced v4f nontemporal stores.
// ---------------------------------------------------------------------------
struct GemmLds {
  union {
    struct { unsigned short A_s[128 * 128]; unsigned short B_s[128 * 128]; } ab;
    float c_s[128][132];
  };
};

__global__ __launch_bounds__(256) void gemm_kernel(const unsigned short* __restrict__ A,
                                                   const unsigned short* __restrict__ Bm,
                                                   float* __restrict__ Cc) {
  __shared__ GemmLds sh;
  unsigned short* A_s = sh.ab.A_s;
  unsigned short* B_s = sh.ab.B_s;
  int m0 = blockIdx.y * 128;
  int n0 = blockIdx.x * 128;
  int tid = threadIdx.x;

#pragma unroll
  for (int it = 0; it < 8; ++it) {
    int lin = it * 256 + tid;
    int row = lin >> 4, slot = lin & 15;
    int sw = slot ^ (row & 7);
    uint4 va = *(const uint4*)(A + ((size_t)(m0 + row)) * 128 + slot * 8);
    *(uint4*)(A_s + row * 128 + sw * 8) = va;
    uint4 vb = *(const uint4*)(Bm + ((size_t)(n0 + row)) * 128 + slot * 8);
    *(uint4*)(B_s + row * 128 + sw * 8) = vb;
  }
  __syncthreads();

  int lane = tid & 63;
  int w = tid >> 6;
  int wm = (w >> 1) * 64, wn = (w & 1) * 64;
  int lr = lane & 15, g = lane >> 4;

  v4f acc[4][4];
#pragma unroll
  for (int mf = 0; mf < 4; ++mf)
#pragma unroll
    for (int nf = 0; nf < 4; ++nf) {
      v4f z = {0.f, 0.f, 0.f, 0.f};
      acc[mf][nf] = z;
    }

#pragma unroll
  for (int ks = 0; ks < 4; ++ks) {
    int kg = ks * 4 + g;
    v8s a[4], bfr[4];
#pragma unroll
    for (int mf = 0; mf < 4; ++mf) {
      int row = wm + mf * 16 + lr;
      a[mf] = *(v8s*)(A_s + row * 128 + ((kg ^ (row & 7)) * 8));
    }
#pragma unroll
    for (int nf = 0; nf < 4; ++nf) {
      int row = wn + nf * 16 + lr;
      bfr[nf] = *(v8s*)(B_s + row * 128 + ((kg ^ (row & 7)) * 8));
    }
#pragma unroll
    for (int mf = 0; mf < 4; ++mf)
#pragma unroll
      for (int nf = 0; nf < 4; ++nf)
        acc[mf][nf] = __builtin_amdgcn_mfma_f32_16x16x32_bf16(a[mf], bfr[nf], acc[mf][nf], 0, 0, 0);
  }

  // ---- epilogue: acc -> LDS, then coalesced nt stores
  __syncthreads();
#pragma unroll
  for (int mf = 0; mf < 4; ++mf)
#pragma unroll
    for (int reg = 0; reg < 4; ++reg) {
      int row = wm + mf * 16 + g * 4 + reg;
#pragma unroll
      for (int nf = 0; nf < 4; ++nf)
        sh.c_s[row][wn + nf * 16 + lr] = acc[mf][nf][reg];
    }
  __syncthreads();

  int slot = tid & 31;
  int rsub = tid >> 5;
  bool edge = (n0 + 128 > QQ);
#pragma unroll
  for (int it = 0; it < 16; ++it) {
    int row = it * 8 + rsub;
    int n = n0 + slot * 4;
    v4f v = *(v4f*)(&sh.c_s[row][slot * 4]);
    float* crow = Cc + (size_t)(m0 + row) * QQ;
    if (!edge) {
      __builtin_nontemporal_store(v, (v4f*)(crow + n));
    } else {
      if (n + 3 < QQ) {
        __builtin_nontemporal_store(v, (v4f*)(crow + n));
      } else {
        if (n + 0 < QQ) crow[n + 0] = v.x;
        if (n + 1 < QQ) crow[n + 1] = v.y;
        if (n + 2 < QQ) crow[n + 2] = v.z;
        if (n + 3 < QQ) crow[n + 3] = v.w;
      }
    }
  }
}

// ---------------------------------------------------------------------------
extern "C" void kernel_launch(void* const* d_in, const int* in_sizes, int n_in,
                              void* d_out, int out_size, void* d_ws, size_t ws_size,
                              hipStream_t stream) {
  (void)in_sizes; (void)n_in; (void)out_size; (void)ws_size;
  const int*   idx   = (const int*)d_in[0];
  const float* preW  = (const float*)d_in[1];
  const float* filtW = (const float*)d_in[2];
  const float* gateW = (const float*)d_in[3];
  const float* resW  = (const float*)d_in[4];
  const float* skipW = (const float*)d_in[5];
  const float* W1    = (const float*)d_in[6];
  const float* W2    = (const float*)d_in[7];
  float* out = (float*)d_out;

  char* ws = (char*)d_ws;
  float* skip = (float*)(ws);                              // 3,670,016 B
  unsigned short* h1  = (unsigned short*)(ws + 3670016);   // 1,835,008 B
  unsigned short* W2T = (unsigned short*)(ws + 5505024);   // 4,194,304 B  (~9.7 MB)

  w2t_kernel<<<dim3(NPAD / 64), 256, 0, stream>>>(W2, W2T);
  fused_layers_kernel<<<dim3(OUTW / WCH, BB), 1024, 0, stream>>>(idx, preW, filtW, gateW,
                                                                 resW, skipW, skip);
  h1_kernel<<<dim3(MROWS / 32), 256, 0, stream>>>(skip, W1, h1);
  gemm_kernel<<<dim3(NPAD / 128, MROWS / 128), 256, 0, stream>>>(h1, W2T, out);
}